// Round 2
// baseline (115.162 us; speedup 1.0000x reference)
//
#include <hip/hip_runtime.h>
#include <stdint.h>

// Encoder: B=2,E=512,T=2048,H=8,dh=64, local window |i-j|<=64
// R10: identical to R9 (never measured — two GPU acquisition timeouts).
//     Audit of the R9 attention rewrite found no defects; resubmitting
//     unchanged so the first successful bench measures exactly one
//     structural change vs the 115.1us baseline.
// R9: rewrite k_attention as barrier-free per-wave-rows structure.
//     - wave w owns 16 query rows; row max/sum via 16-lane shfl_xor only
//       (drops both LDS reductions and all 5 __syncthreads).
//     - K and V^T read directly from global as MFMA B-fragments (L2-hot,
//       4 MB each); kills 48 KB/block staging -> LDS 63KB -> 25.6KB (P only,
//       wave-private slab -> lgkmcnt(0) instead of barrier).
//     - window-aware tile skip: 10/12 QK^T key tiles, 5/6 PV k-slots.
//     - OOB keys: clamped addresses (finite data) + mask replace.
//     - __launch_bounds__(256,4): cap VGPR 128 -> 4 blocks/CU (was 2).
//     - s_setprio(1) around MFMA clusters (m191: +4-7% independent-wave attn).
// GEMMs unchanged from measured-best R6/R8 config.

#define DEVI __device__ __forceinline__

typedef __attribute__((ext_vector_type(8))) short bf16x8;   // 8 bf16 in 4 VGPRs
typedef __attribute__((ext_vector_type(4))) float f32x4;

DEVI unsigned short f2bf(float f) {               // RNE float->bf16
  unsigned u = __float_as_uint(f);
  u += 0x7fffu + ((u >> 16) & 1u);
  return (unsigned short)(u >> 16);
}
DEVI float bf2f(unsigned short h) { return __uint_as_float(((unsigned)h) << 16); }

#define GLL16(gp, lp)                                                          \
  __builtin_amdgcn_global_load_lds(                                            \
      (const __attribute__((address_space(1))) void*)(gp),                     \
      (__attribute__((address_space(3))) void*)(lp), 16, 0, 0)

#define MFMA(a, b, c) __builtin_amdgcn_mfma_f32_16x16x32_bf16((a), (b), (c), 0, 0, 0)

// ---------------------------------------------------------------------------
// K0: blockIdx.y<16: x[B,E,T] fp32 -> xT[B*T,512] bf16 (transpose)
//     blockIdx.y==16: w_in/w_out fp32 -> bf16 hi (128 rider blocks)
__global__ __launch_bounds__(256) void k_prep(
    const float* __restrict__ x, const float* __restrict__ w_in,
    const float* __restrict__ w_out, unsigned short* __restrict__ xh,
    unsigned short* __restrict__ wih, unsigned short* __restrict__ woh) {
  const int tid = threadIdx.x;
  if (blockIdx.y == 16) {  // weight convert rider: 128 blocks x 8192 elems
    int cb = (blockIdx.z << 6) | blockIdx.x;
    const float* src;
    unsigned short* dst;
    int base;
    if (cb < 96) {        // 96*8192 = 786432 = w_in exactly
      src = w_in; dst = wih; base = cb * 8192;
    } else {              // 32*8192 = 262144 = w_out exactly
      src = w_out; dst = woh; base = (cb - 96) * 8192;
    }
#pragma unroll
    for (int k = 0; k < 8; k++) {
      int idx = base + (k * 256 + tid) * 4;
      float4 v = *(const float4*)&src[idx];
      ushort4 o;
      o.x = f2bf(v.x); o.y = f2bf(v.y); o.z = f2bf(v.z); o.w = f2bf(v.w);
      *(ushort4*)&dst[idx] = o;
    }
    return;
  }
  __shared__ float tile[32][33];
  const int b = blockIdx.z, e0 = blockIdx.y * 32, t0 = blockIdx.x * 32;
  const int j = tid & 31, i = tid >> 5;  // i: 0..7
#pragma unroll
  for (int rr = 0; rr < 4; rr++) {
    int e = e0 + i + rr * 8;
    tile[i + rr * 8][j] = x[((size_t)b * 512 + e) * 2048 + t0 + j];  // coalesced t
  }
  __syncthreads();
#pragma unroll
  for (int rr = 0; rr < 4; rr++) {
    int t = t0 + i + rr * 8;
    float v = tile[j][i + rr * 8];
    size_t o = ((size_t)b * 2048 + t) * 512 + e0 + j;  // coalesced e
    xh[o] = f2bf(v);
  }
}

// ---------------------------------------------------------------------------
// QKV GEMM: C[m,n] = sum_k Ah[m,k]*Bh[n,k] + bias[n], 128x128 tile, BK=32.
// Grid: 384 linear, XCD-swizzled. Epilogue: Q(*0.125)/K -> [B,H,T,64] bf16,
// V -> TRANSPOSED [B,H,64,T] bf16 (packed ushort4, 4 consecutive t/thread).
__global__ __launch_bounds__(256) void k_gemm_qkv(
    const unsigned short* __restrict__ Ahg, const unsigned short* __restrict__ Bhg,
    const float* __restrict__ bias, unsigned short* __restrict__ Qs,
    unsigned short* __restrict__ Kks, unsigned short* __restrict__ VvT) {
  const int KD = 512;
  __shared__ __align__(16) unsigned short Ah_s[128 * 32];
  __shared__ __align__(16) unsigned short Bh_s[128 * 32];
  const int tid = threadIdx.x, lane = tid & 63, w = tid >> 6;
  // XCD swizzle: dispatch heuristic xcd = bid%8; 48 blocks/XCD = 4m x 12n slab
  const int bid = blockIdx.x;
  const int xcd = bid & 7, j5 = bid >> 3;
  const int m0 = (xcd * 4 + j5 / 12) * 128, n0 = (j5 % 12) * 128;
  const int wm = (w >> 1) * 64, wn = (w & 1) * 64;

  f32x4 acc[4][4];
#pragma unroll
  for (int i = 0; i < 4; i++)
#pragma unroll
    for (int j = 0; j < 4; j++) acc[i][j] = (f32x4){0.f, 0.f, 0.f, 0.f};

  const int srw = lane >> 2, sc = (lane & 3) * 8;
  const size_t b0 = (size_t)(n0 + w * 32 + srw) * KD + sc;
  const size_t b1 = b0 + (size_t)16 * KD;
  unsigned short* lB0 = &Bh_s[(w * 32) * 32];
  unsigned short* lB1 = &Bh_s[(w * 32 + 16) * 32];
  const size_t a0 = (size_t)(m0 + w * 32 + srw) * KD + sc;
  const size_t a1 = a0 + (size_t)16 * KD;
  unsigned short* lAh0 = &Ah_s[(w * 32) * 32];
  unsigned short* lAh1 = &Ah_s[(w * 32 + 16) * 32];

  const int fm = lane & 15, fq = (lane >> 4) * 8;

  for (int k0 = 0; k0 < KD; k0 += 32) {
    __syncthreads();
    GLL16(Ahg + a0 + k0, lAh0);
    GLL16(Ahg + a1 + k0, lAh1);
    GLL16(Bhg + b0 + k0, lB0);
    GLL16(Bhg + b1 + k0, lB1);
    __builtin_amdgcn_s_waitcnt(0);
    __syncthreads();

    bf16x8 ah[4], bh[4];
#pragma unroll
    for (int i = 0; i < 4; i++) {
      ah[i] = *(const bf16x8*)&Ah_s[(wm + i * 16 + fm) * 32 + fq];
      bh[i] = *(const bf16x8*)&Bh_s[(wn + i * 16 + fm) * 32 + fq];
    }
#pragma unroll
    for (int i = 0; i < 4; i++)
#pragma unroll
      for (int j = 0; j < 4; j++)
        acc[i][j] = MFMA(ah[i], bh[j], acc[i][j]);
  }

  // epilogue: C/D layout col=lane&15, row=quad*4+r  [m89-verified]
  const int quad = lane >> 4;
#pragma unroll
  for (int i = 0; i < 4; i++)
#pragma unroll
    for (int j = 0; j < 4; j++) {
      int gn = n0 + wn + j * 16 + fm;
      float bv = bias[gn];
      int sec = gn >> 9, cc = gn & 511;
      int h = cc >> 6, d = cc & 63;
      int gm0 = m0 + wm + i * 16 + quad * 4;       // 4-aligned t base
      int bb = gm0 >> 11, t = gm0 & 2047;
      if (sec == 2) {  // V^T [B,H,64,2048]: 4 consecutive t -> one 8B store
        ushort4 pk;
        pk.x = f2bf(acc[i][j][0] + bv);
        pk.y = f2bf(acc[i][j][1] + bv);
        pk.z = f2bf(acc[i][j][2] + bv);
        pk.w = f2bf(acc[i][j][3] + bv);
        *(ushort4*)&VvT[(((size_t)(bb * 8 + h)) * 64 + d) * 2048 + t] = pk;
      } else {
        unsigned short* dst = sec == 0 ? Qs : Kks;
        float mul = sec == 0 ? 0.125f : 1.0f;  // 1/sqrt(64), exact
#pragma unroll
        for (int r = 0; r < 4; r++) {
          float v = (acc[i][j][r] + bv) * mul;
          dst[(((size_t)(bb * 8 + h)) * 2048 + t + r) * 64 + d] = f2bf(v);
        }
      }
    }
}

// ---------------------------------------------------------------------------
// Out-proj GEMM fused with final transpose * x + relu. Single-pass bf16.
// C[m,n] = sum_k Ah[m,k]*Bh[n,k] + bias[n]; tile 64m x 128n, grid 256.
// Epilogue: LDS transpose -> out[b,e,t] = relu(C[b,t,e] * x[b,e,t]).
__global__ __launch_bounds__(256) void k_gemm_out(
    const unsigned short* __restrict__ Ahg, const unsigned short* __restrict__ Bhg,
    const float* __restrict__ bias, const float* __restrict__ x,
    float* __restrict__ out) {
  const int KD = 512;
  __shared__ __align__(16) union {
    struct {
      unsigned short Ah[64 * 32];
      unsigned short Bh[128 * 32];
    } st;                       // 12 KB staging
    float tile[64][129];        // 32.25 KB epilogue transpose
  } u;
  const int tid = threadIdx.x, lane = tid & 63, w = tid >> 6;
  // XCD swizzle: 32 blocks/XCD = 8m x 4n slab (A 0.5 MB + B 0.5 MB in L2)
  const int bid = blockIdx.x;
  const int xcd = bid & 7, j5 = bid >> 3;
  const int m0 = (xcd * 8 + (j5 >> 2)) * 64, n0 = (j5 & 3) * 128;
  const int wm = (w >> 1) * 32, wn = (w & 1) * 64;

  f32x4 acc[2][4];
#pragma unroll
  for (int i = 0; i < 2; i++)
#pragma unroll
    for (int j = 0; j < 4; j++) acc[i][j] = (f32x4){0.f, 0.f, 0.f, 0.f};

  const int srw = lane >> 2, sc = (lane & 3) * 8;
  const size_t b0 = (size_t)(n0 + w * 32 + srw) * KD + sc;
  const size_t b1 = b0 + (size_t)16 * KD;
  const size_t a0 = (size_t)(m0 + w * 16 + srw) * KD + sc;
  unsigned short* lB0 = &u.st.Bh[(w * 32) * 32];
  unsigned short* lB1 = &u.st.Bh[(w * 32 + 16) * 32];
  unsigned short* lAh0 = &u.st.Ah[(w * 16) * 32];

  const int fm = lane & 15, fq = (lane >> 4) * 8;

  for (int k0 = 0; k0 < KD; k0 += 32) {
    __syncthreads();
    GLL16(Ahg + a0 + k0, lAh0);
    GLL16(Bhg + b0 + k0, lB0);
    GLL16(Bhg + b1 + k0, lB1);
    __builtin_amdgcn_s_waitcnt(0);
    __syncthreads();

    bf16x8 ah[2], bh[4];
#pragma unroll
    for (int i = 0; i < 2; i++)
      ah[i] = *(const bf16x8*)&u.st.Ah[(wm + i * 16 + fm) * 32 + fq];
#pragma unroll
    for (int j = 0; j < 4; j++)
      bh[j] = *(const bf16x8*)&u.st.Bh[(wn + j * 16 + fm) * 32 + fq];
#pragma unroll
    for (int i = 0; i < 2; i++)
#pragma unroll
      for (int j = 0; j < 4; j++)
        acc[i][j] = MFMA(ah[i], bh[j], acc[i][j]);
  }

  __syncthreads();  // all frag reads done before tile overwrites staging
  // write acc+bias into transpose tile: tile[t_local][e_local]
  const int quad = lane >> 4;
#pragma unroll
  for (int i = 0; i < 2; i++)
#pragma unroll
    for (int j = 0; j < 4; j++) {
      int ln = wn + j * 16 + fm;
      float bv = bias[n0 + ln];
#pragma unroll
      for (int r = 0; r < 4; r++) {
        int lm = wm + i * 16 + quad * 4 + r;
        u.tile[lm][ln] = acc[i][j][r] + bv;
      }
    }
  __syncthreads();

  // out[b,e,t] = relu(tile[t][e] * x[b,e,t]); coalesced along t
  const int bb = m0 >> 11, t0 = m0 & 2047;
  const int tt = tid & 63, e0w = tid >> 6;
#pragma unroll
  for (int k = 0; k < 32; k++) {
    int ee = e0w + k * 4;
    size_t o = ((size_t)bb * 512 + n0 + ee) * 2048 + t0 + tt;
    float v = u.tile[tt][ee] * x[o];
    out[o] = fmaxf(v, 0.f);
  }
}

// ---------------------------------------------------------------------------
// K2: local attention, barrier-free. Block = (b,h, 64 queries); wave w owns
// query rows [q0+w*16, q0+w*16+16). K/V^T fragments read DIRECTLY from
// global (L2-hot, 4 MB each). Only LDS use: wave-private P transpose slab.
#define PSTR 200  // P row stride (bf16): 400B; b128 frag reads land 8 dw/bank
__global__ __launch_bounds__(256, 4) void k_attention(
    const unsigned short* __restrict__ Qs, const unsigned short* __restrict__ Kks,
    const unsigned short* __restrict__ VvT, unsigned short* __restrict__ ctx_hi) {
  __shared__ __align__(16) unsigned short P_s[64 * PSTR];  // 25.6 KB

  const int tid = threadIdx.x, lane = tid & 63, w = tid >> 6;
  const int q0 = blockIdx.x * 64;
  const int bh = blockIdx.y;
  const int j0 = q0 - 64;                    // window base key
  const size_t base = (size_t)bh * 2048 * 64;
  const int fm = lane & 15, quad = lane >> 4;

  // Q A-fragments for this wave's 16 rows (pre-scaled by 1/8 in QKV epilogue)
  bf16x8 aq[2];
  {
    const size_t qb = base + (size_t)(q0 + w * 16 + fm) * 64 + quad * 8;
#pragma unroll
    for (int ks = 0; ks < 2; ks++)
      aq[ks] = *(const bf16x8*)&Qs[qb + ks * 32];
  }

  // S = Q @ K^T over 10 key tiles ct = ct0..ct0+9. This range covers both
  // the validity window of this wave's rows AND exactly the P columns PV
  // reads (cols [32*ks0, 32*ks0+160)), so skipped/masked tiles give P=0.
  const int ct0 = (w >> 1) * 2;
  f32x4 sa[10];
#pragma unroll
  for (int u2 = 0; u2 < 10; u2++) sa[u2] = (f32x4){0.f, 0.f, 0.f, 0.f};
  __builtin_amdgcn_s_setprio(1);
#pragma unroll
  for (int u2 = 0; u2 < 10; u2++) {
    int jr = j0 + (ct0 + u2) * 16 + fm;
    jr = jr < 0 ? 0 : (jr > 2047 ? 2047 : jr);     // clamp: finite data, masked below
    const unsigned short* kp = &Kks[base + (size_t)jr * 64 + quad * 8];
#pragma unroll
    for (int ks = 0; ks < 2; ks++) {
      bf16x8 bk = *(const bf16x8*)&kp[ks * 32];
      sa[u2] = MFMA(aq[ks], bk, sa[u2]);
    }
  }
  __builtin_amdgcn_s_setprio(0);

  // mask (REPLACE, kills clamped-row garbage) + per-row max
  float rm[4], rs[4], inv[4];
#pragma unroll
  for (int r = 0; r < 4; r++) rm[r] = -1e30f;
#pragma unroll
  for (int u2 = 0; u2 < 10; u2++) {
    int jj = (ct0 + u2) * 16 + fm;               // block-local key col
    int jg = j0 + jj;
    bool jok = (jg >= 0) && (jg < 2048);
#pragma unroll
    for (int r = 0; r < 4; r++) {
      int ii = w * 16 + quad * 4 + r;            // block-local query row
      bool ok = jok && (jj >= ii) && (jj <= ii + 128);
      float sv = ok ? sa[u2][r] : -1e30f;
      sa[u2][r] = sv;
      rm[r] = fmaxf(rm[r], sv);
    }
  }
  // row reduce over the 16 fm lanes only (xor 1,2,4,8 stays inside quad group)
#pragma unroll
  for (int off = 1; off < 16; off <<= 1)
#pragma unroll
    for (int r = 0; r < 4; r++) rm[r] = fmaxf(rm[r], __shfl_xor(rm[r], off));
  // exp + row sum (masked entries underflow to exactly 0)
#pragma unroll
  for (int r = 0; r < 4; r++) rs[r] = 0.f;
#pragma unroll
  for (int u2 = 0; u2 < 10; u2++)
#pragma unroll
    for (int r = 0; r < 4; r++) {
      float e = __expf(sa[u2][r] - rm[r]);
      sa[u2][r] = e;
      rs[r] += e;
    }
#pragma unroll
  for (int off = 1; off < 16; off <<= 1)
#pragma unroll
    for (int r = 0; r < 4; r++) rs[r] += __shfl_xor(rs[r], off);
#pragma unroll
  for (int r = 0; r < 4; r++) inv[r] = 1.0f / rs[r];

  // P (bf16) -> wave-private LDS slab (C layout -> A layout transpose).
  // Intra-wave only: lgkmcnt(0) + sched fence instead of a barrier.
#pragma unroll
  for (int u2 = 0; u2 < 10; u2++)
#pragma unroll
    for (int r = 0; r < 4; r++) {
      int row = w * 16 + quad * 4 + r;
      P_s[row * PSTR + (ct0 + u2) * 16 + fm] = f2bf(sa[u2][r] * inv[r]);
    }
  asm volatile("s_waitcnt lgkmcnt(0)" ::: "memory");
  __builtin_amdgcn_sched_barrier(0);

  // ctx = P @ V^T-rows direct from global; ks covers exactly the 5 32-key
  // slots intersecting this wave's window (P cols [32*ks0, 32*ks0+160)).
  const int ks0 = w >> 1;
  f32x4 oa[4];
#pragma unroll
  for (int dt = 0; dt < 4; dt++) oa[dt] = (f32x4){0.f, 0.f, 0.f, 0.f};
  __builtin_amdgcn_s_setprio(1);
#pragma unroll
  for (int ku = 0; ku < 5; ku++) {
    int ks = ks0 + ku;
    bf16x8 ap = *(const bf16x8*)&P_s[(w * 16 + fm) * PSTR + ks * 32 + quad * 8];
    int j = j0 + ks * 32 + quad * 8;             // 8-aligned chunk: fully in or out
    j = (j < 0 || j > 2040) ? 0 : j;             // OOB chunk -> valid addr (P=0 there)
    const unsigned short* vp = &VvT[base + j];
#pragma unroll
    for (int dt = 0; dt < 4; dt++) {
      bf16x8 bv = *(const bf16x8*)&vp[(size_t)(dt * 16 + fm) * 2048];
      oa[dt] = MFMA(ap, bv, oa[dt]);
    }
  }
  __builtin_amdgcn_s_setprio(0);

  // write ctx bf16 [B*T, 512]
  const int bb = bh >> 3, h = bh & 7;
#pragma unroll
  for (int dt = 0; dt < 4; dt++)
#pragma unroll
    for (int r = 0; r < 4; r++) {
      int t = q0 + w * 16 + quad * 4 + r;
      int c = h * 64 + dt * 16 + fm;
      ctx_hi[((size_t)(bb * 2048 + t)) * 512 + c] = f2bf(oa[dt][r]);
    }
}

// ---------------------------------------------------------------------------
extern "C" void kernel_launch(void* const* d_in, const int* in_sizes, int n_in,
                              void* d_out, int out_size, void* d_ws, size_t ws_size,
                              hipStream_t stream) {
  const float* x = (const float*)d_in[0];
  const float* w_in = (const float*)d_in[1];
  const float* b_in = (const float*)d_in[2];
  const float* w_out = (const float*)d_in[3];
  const float* b_out = (const float*)d_in[4];
  float* out = (float*)d_out;

  uint8_t* ws = (uint8_t*)d_ws;
  unsigned short* xT_hi = (unsigned short*)(ws + 0);           // 4 MiB
  unsigned short* wih   = (unsigned short*)(ws + 8388608);     // 1.5 MiB
  unsigned short* woh   = (unsigned short*)(ws + 9961472);     // 0.5 MiB
  unsigned short* Qs    = (unsigned short*)(ws + 12582912);    // 4 MiB
  unsigned short* Kk    = (unsigned short*)(ws + 16777216);    // 4 MiB
  unsigned short* VvT   = (unsigned short*)(ws + 20971520);    // 4 MiB [B,H,64,T]
  unsigned short* ctxh  = (unsigned short*)(ws + 25165824);    // 4 MiB

  k_prep<<<dim3(64, 17, 2), 256, 0, stream>>>(x, w_in, w_out, xT_hi, wih, woh);
  k_gemm_qkv<<<384, 256, 0, stream>>>(xT_hi, wih, b_in, Qs, Kk, VvT);
  k_attention<<<dim3(32, 16), 256, 0, stream>>>(Qs, Kk, VvT, ctxh);
  k_gemm_out<<<256, 256, 0, stream>>>(ctxh, woh, b_out, x, out);
}